// Round 1
// baseline (362.596 us; speedup 1.0000x reference)
//
#include <hip/hip_runtime.h>
#include <stdint.h>

#define ROW_LEN 2048
#define THREADS 256
#define EPT (ROW_LEN / THREADS)   // 8 elements per thread
#define NWAVES (THREADS / 64)     // 4 waves

// padded index for the u64 kv array to break power-of-2 bank conflicts
#define KVIDX(i) ((i) + ((i) >> 4))
#define KV_PAD_LEN (ROW_LEN + (ROW_LEN >> 4))   // 2176

__global__ __launch_bounds__(THREADS) void listmle_kernel(
    const float* __restrict__ preds,
    const float* __restrict__ labels,
    float* __restrict__ out,
    int nrows)
{
    __shared__ uint64_t kv[KV_PAD_LEN];   // ~17.4 KB
    __shared__ float    ex[ROW_LEN];      // 8 KB
    __shared__ float    wmax[NWAVES];
    __shared__ float    wsum[NWAVES];
    __shared__ float    wred[NWAVES];

    const int row  = blockIdx.x;
    if (row >= nrows) return;
    const float* __restrict__ p  = preds  + (size_t)row * ROW_LEN;
    const float* __restrict__ lb = labels + (size_t)row * ROW_LEN;
    const int tid  = threadIdx.x;
    const int lane = tid & 63;
    const int wave = tid >> 6;

    // ---- load: pack (inverted-ordered label bits | pred bits), track max & sum
    float lmax = -INFINITY;
    float lsum = 0.f;
#pragma unroll
    for (int e = 0; e < EPT; ++e) {
        int i = tid + e * THREADS;                 // coalesced
        float pv = p[i];
        float lv = lb[i];
        uint32_t u    = __float_as_uint(lv);
        uint32_t mask = (u & 0x80000000u) ? 0xFFFFFFFFu : 0x80000000u;
        uint32_t key  = ~(u ^ mask);               // ascending key == descending label
        kv[KVIDX(i)] = ((uint64_t)key << 32) | (uint64_t)__float_as_uint(pv);
        lmax = fmaxf(lmax, pv);
        lsum += pv;
    }

    // ---- block reduce max & sum
#pragma unroll
    for (int o = 32; o > 0; o >>= 1) {
        lmax = fmaxf(lmax, __shfl_down(lmax, o));
        lsum += __shfl_down(lsum, o);
    }
    if (lane == 0) { wmax[wave] = lmax; wsum[wave] = lsum; }
    __syncthreads();
    const float m      = fmaxf(fmaxf(wmax[0], wmax[1]), fmaxf(wmax[2], wmax[3]));
    const float rowsum = wsum[0] + wsum[1] + wsum[2] + wsum[3];

    // ---- bitonic sort (ascending u64 == descending label), 2048 elems
    for (int k = 2; k <= ROW_LEN; k <<= 1) {
        for (int j = k >> 1; j > 0; j >>= 1) {
            __syncthreads();
#pragma unroll
            for (int s = 0; s < (ROW_LEN / 2) / THREADS; ++s) {   // 4 pairs/thread
                int w  = tid + s * THREADS;
                int i  = ((w & ~(j - 1)) << 1) | (w & (j - 1));
                int p2 = i | j;
                bool up = ((i & k) == 0);
                uint64_t a = kv[KVIDX(i)];
                uint64_t b = kv[KVIDX(p2)];
                bool sw = up ? (a > b) : (a < b);
                if (sw) { kv[KVIDX(i)] = b; kv[KVIDX(p2)] = a; }
            }
        }
    }
    __syncthreads();

    // ---- ex_i = exp(pred_sorted_i - m)
#pragma unroll
    for (int e = 0; e < EPT; ++e) {
        int i = tid + e * THREADS;
        float pv = __uint_as_float((uint32_t)(kv[KVIDX(i)] & 0xFFFFFFFFull));
        ex[i] = __expf(pv - m);
    }

    // ---- inclusive suffix scan (Hillis-Steele), genuinely from the tail
    for (int d = 1; d < ROW_LEN; d <<= 1) {
        float t[EPT];
        __syncthreads();
#pragma unroll
        for (int e = 0; e < EPT; ++e) {
            int i = tid + e * THREADS;
            float v = ex[i];
            if (i + d < ROW_LEN) v += ex[i + d];
            t[e] = v;
        }
        __syncthreads();
#pragma unroll
        for (int e = 0; e < EPT; ++e) ex[tid + e * THREADS] = t[e];
    }
    __syncthreads();

    // ---- sum of log(S_i)
    float acc = 0.f;
#pragma unroll
    for (int e = 0; e < EPT; ++e) {
        int i = tid + e * THREADS;
        acc += __logf(ex[i]);
    }
#pragma unroll
    for (int o = 32; o > 0; o >>= 1) acc += __shfl_down(acc, o);
    if (lane == 0) wred[wave] = acc;
    __syncthreads();
    if (tid == 0) {
        float total = wred[0] + wred[1] + wred[2] + wred[3]
                      + (float)ROW_LEN * m - rowsum;
        atomicAdd(out, total);
    }
}

extern "C" void kernel_launch(void* const* d_in, const int* in_sizes, int n_in,
                              void* d_out, int out_size, void* d_ws, size_t ws_size,
                              hipStream_t stream) {
    const float* preds  = (const float*)d_in[0];
    const float* labels = (const float*)d_in[1];
    float* out = (float*)d_out;
    const int total = in_sizes[0];
    const int nrows = total / ROW_LEN;

    hipMemsetAsync(d_out, 0, (size_t)out_size * sizeof(float), stream);
    listmle_kernel<<<nrows, THREADS, 0, stream>>>(preds, labels, out, nrows);
}

// Round 2
// 231.313 us; speedup vs baseline: 1.5676x; 1.5676x over previous
//
#include <hip/hip_runtime.h>
#include <stdint.h>

#define ROW_LEN 2048
#define THREADS 256
#define EPT 8
#define NWAVES 4

__device__ __forceinline__ void ce(uint64_t &a, uint64_t &b, bool up) {
    uint64_t mn = a < b ? a : b;
    uint64_t mx = a < b ? b : a;
    a = up ? mn : mx;
    b = up ? mx : mn;
}

__global__ __launch_bounds__(THREADS) void listmle_kernel(
    const float* __restrict__ preds,
    const float* __restrict__ labels,
    float* __restrict__ out,
    int nrows)
{
    __shared__ uint64_t xbuf[ROW_LEN];   // 16 KB, strided [s][t] layout
    __shared__ float wmax[NWAVES], wsum[NWAVES], wtt[NWAVES], wred[NWAVES];

    const int row  = blockIdx.x;
    if (row >= nrows) return;
    const int t    = threadIdx.x;
    const int lane = t & 63;
    const int wave = t >> 6;
    const int base = t * EPT;

    const float* __restrict__ p  = preds  + (size_t)row * ROW_LEN;
    const float* __restrict__ lb = labels + (size_t)row * ROW_LEN;

    // ---- load 8 consecutive preds/labels per thread (2x float4 each)
    float4 p0 = ((const float4*)p)[t * 2];
    float4 p1 = ((const float4*)p)[t * 2 + 1];
    float4 l0 = ((const float4*)lb)[t * 2];
    float4 l1 = ((const float4*)lb)[t * 2 + 1];
    float pv[8] = {p0.x, p0.y, p0.z, p0.w, p1.x, p1.y, p1.z, p1.w};
    float lv[8] = {l0.x, l0.y, l0.z, l0.w, l1.x, l1.y, l1.z, l1.w};

    // ---- pack (order-inverted label bits | pred bits); track max & sum
    uint64_t v[8];
    float lmax = -INFINITY, lsum = 0.f;
#pragma unroll
    for (int s = 0; s < 8; ++s) {
        uint32_t u    = __float_as_uint(lv[s]);
        uint32_t mask = (u & 0x80000000u) ? 0xFFFFFFFFu : 0x80000000u;
        uint32_t key  = ~(u ^ mask);     // ascending u64 == descending label
        v[s] = ((uint64_t)key << 32) | (uint64_t)__float_as_uint(pv[s]);
        lmax = fmaxf(lmax, pv[s]);
        lsum += pv[s];
    }

    // ---- block reduce max & sum (lane-0 chains are well-defined)
#pragma unroll
    for (int o = 32; o > 0; o >>= 1) {
        lmax = fmaxf(lmax, __shfl_down(lmax, o, 64));
        lsum += __shfl_down(lsum, o, 64);
    }
    if (lane == 0) { wmax[wave] = lmax; wsum[wave] = lsum; }
    __syncthreads();
    const float m      = fmaxf(fmaxf(wmax[0], wmax[1]), fmaxf(wmax[2], wmax[3]));
    const float rowsum = wsum[0] + wsum[1] + wsum[2] + wsum[3];

    // ================= bitonic sort, ascending u64 =================
    // Phase 1: k = 2,4,8 entirely intra-thread
#pragma unroll
    for (int k = 2; k <= 8; k <<= 1)
#pragma unroll
        for (int j = k >> 1; j >= 1; j >>= 1)
#pragma unroll
            for (int s = 0; s < 8; ++s)
                if (!(s & j)) {
                    bool up = (((base + s) & k) == 0);
                    ce(v[s], v[s | j], up);
                }

    // Phase 2: k = 16 .. 2048
#pragma unroll
    for (int k = 16; k <= ROW_LEN; k <<= 1) {
        const bool up = ((base & k) == 0);   // uniform across the thread's 8
#pragma unroll
        for (int j = k >> 1; j >= 8; j >>= 1) {
            const int bit = j >> 3;          // thread-xor distance
            if (bit >= 64) {
                // cross-wave exchange through LDS (only j = 512, 1024)
                __syncthreads();
#pragma unroll
                for (int s = 0; s < 8; ++s) xbuf[s * THREADS + t] = v[s];
                __syncthreads();
                const bool keepmin = (up == ((t & bit) == 0));
#pragma unroll
                for (int s = 0; s < 8; ++s) {
                    uint64_t o = xbuf[s * THREADS + (t ^ bit)];
                    uint64_t mn = v[s] < o ? v[s] : o;
                    uint64_t mx = v[s] < o ? o : v[s];
                    v[s] = keepmin ? mn : mx;
                }
            } else {
                // in-wave exchange via shuffle
                const bool keepmin = (up == ((t & bit) == 0));
#pragma unroll
                for (int s = 0; s < 8; ++s) {
                    uint64_t o = (uint64_t)__shfl_xor((unsigned long long)v[s], bit, 64);
                    uint64_t mn = v[s] < o ? v[s] : o;
                    uint64_t mx = v[s] < o ? o : v[s];
                    v[s] = keepmin ? mn : mx;
                }
            }
        }
        // local tail j = 4,2,1 (direction uniform per thread)
#pragma unroll
        for (int j = 4; j >= 1; j >>= 1)
#pragma unroll
            for (int s = 0; s < 8; ++s)
                if (!(s & j)) ce(v[s], v[s | j], up);
    }

    // ================= epilogue =================
    // e_s = exp(pred_sorted - m); chunk sum
    float e[8];
    float csum = 0.f;
#pragma unroll
    for (int s = 0; s < 8; ++s) {
        float ps = __uint_as_float((uint32_t)(v[s] & 0xFFFFFFFFull));
        e[s] = __expf(ps - m);
        csum += e[s];
    }

    // inclusive suffix scan of chunk sums within wave
    float x = csum;
#pragma unroll
    for (int o = 1; o < 64; o <<= 1) {
        float y = __shfl_down(x, o, 64);
        if (lane + o < 64) x += y;
    }
    if (lane == 0) wtt[wave] = x;        // wave totals
    __syncthreads();
    float after = 0.f;
#pragma unroll
    for (int w = 0; w < NWAVES; ++w)
        if (w > wave) after += wtt[w];

    // exclusive suffix for this thread's chunk, then serial log-accumulate
    float run = (x - csum) + after;
    float acc = 0.f;
#pragma unroll
    for (int s = 7; s >= 0; --s) {
        run += e[s];
        acc += __logf(run);
    }

    // ---- block reduce acc, one atomic per row
#pragma unroll
    for (int o = 32; o > 0; o >>= 1) acc += __shfl_down(acc, o, 64);
    if (lane == 0) wred[wave] = acc;
    __syncthreads();
    if (t == 0) {
        float total = wred[0] + wred[1] + wred[2] + wred[3]
                      + (float)ROW_LEN * m - rowsum;
        atomicAdd(out, total);
    }
}

extern "C" void kernel_launch(void* const* d_in, const int* in_sizes, int n_in,
                              void* d_out, int out_size, void* d_ws, size_t ws_size,
                              hipStream_t stream) {
    const float* preds  = (const float*)d_in[0];
    const float* labels = (const float*)d_in[1];
    float* out = (float*)d_out;
    const int total = in_sizes[0];
    const int nrows = total / ROW_LEN;

    hipMemsetAsync(d_out, 0, (size_t)out_size * sizeof(float), stream);
    listmle_kernel<<<nrows, THREADS, 0, stream>>>(preds, labels, out, nrows);
}

// Round 3
// 142.626 us; speedup vs baseline: 2.5423x; 1.6218x over previous
//
#include <hip/hip_runtime.h>
#include <stdint.h>

#define ROW_LEN 2048
#define THREADS 256
#define NWAVES 4

// lane ^ BIT exchange of a 32-bit value within a wave.
// BIT <= 16: single ds_swizzle (bitmode, within 32-lane groups, valid since bit<=16).
// BIT == 32: cross-half, use __shfl_xor (ds_bpermute).
template<int BIT>
__device__ __forceinline__ uint32_t lane_xor32(uint32_t x) {
    if constexpr (BIT < 32) {
        return (uint32_t)__builtin_amdgcn_ds_swizzle((int)x, (BIT << 10) | 0x1F);
    } else {
        return (uint32_t)__shfl_xor((int)x, 32, 64);
    }
}

__device__ __forceinline__ void ce(uint32_t &a, uint32_t &b, bool up) {
    uint32_t mn = min(a, b);
    uint32_t mx = max(a, b);
    a = up ? mn : mx;
    b = up ? mx : mn;
}

// shuffle stages for j = 8*BIT down to j = 8 (BIT .. 1)
template<int BIT>
__device__ __forceinline__ void shuffle_stages(uint32_t v[8], int t, bool up) {
    const bool keepmin = (up == ((t & BIT) == 0));
#pragma unroll
    for (int s = 0; s < 8; ++s) {
        uint32_t o = lane_xor32<BIT>(v[s]);
        uint32_t mn = min(v[s], o);
        uint32_t mx = max(v[s], o);
        v[s] = keepmin ? mn : mx;
    }
    if constexpr (BIT > 1) shuffle_stages<BIT / 2>(v, t, up);
}

// cross-wave stage through LDS (bit = 64 or 128 in thread space)
__device__ __forceinline__ void lds_stage(uint32_t v[8], bool up, int t, int bit,
                                          uint32_t* xbuf) {
    __syncthreads();
#pragma unroll
    for (int s = 0; s < 8; ++s) xbuf[s * THREADS + t] = v[s];
    __syncthreads();
    const bool keepmin = (up == ((t & bit) == 0));
    const int pt = t ^ bit;
#pragma unroll
    for (int s = 0; s < 8; ++s) {
        uint32_t o = xbuf[s * THREADS + pt];
        uint32_t mn = min(v[s], o);
        uint32_t mx = max(v[s], o);
        v[s] = keepmin ? mn : mx;
    }
}

// local tail j = 4,2,1 with per-thread-uniform direction
__device__ __forceinline__ void tail(uint32_t v[8], bool up) {
#pragma unroll
    for (int j = 4; j >= 1; j >>= 1)
#pragma unroll
        for (int s = 0; s < 8; ++s)
            if (!(s & j)) ce(v[s], v[s | j], up);
}

__global__ __launch_bounds__(THREADS) void listmle_kernel(
    const float* __restrict__ preds,
    const float* __restrict__ labels,
    float* __restrict__ out,
    int nrows)
{
    __shared__ uint32_t xbuf[ROW_LEN];   // 8 KB: sort exchange buffer
    __shared__ float    predb[ROW_LEN];  // 8 KB: preds by original index
    __shared__ float wmax[NWAVES], wsum[NWAVES], wtt[NWAVES], wred[NWAVES];

    const int row  = blockIdx.x;
    if (row >= nrows) return;
    const int t    = threadIdx.x;
    const int lane = t & 63;
    const int wave = t >> 6;
    const int base = t * 8;

    const float* __restrict__ p  = preds  + (size_t)row * ROW_LEN;
    const float* __restrict__ lb = labels + (size_t)row * ROW_LEN;

    // ---- load 8 consecutive preds/labels (2x float4 each)
    float4 p0 = ((const float4*)p)[t * 2];
    float4 p1 = ((const float4*)p)[t * 2 + 1];
    float4 l0 = ((const float4*)lb)[t * 2];
    float4 l1 = ((const float4*)lb)[t * 2 + 1];
    float pv[8] = {p0.x, p0.y, p0.z, p0.w, p1.x, p1.y, p1.z, p1.w};
    float lv[8] = {l0.x, l0.y, l0.z, l0.w, l1.x, l1.y, l1.z, l1.w};

    // stash preds in LDS for post-sort gather
    ((float4*)predb)[t * 2]     = p0;
    ((float4*)predb)[t * 2 + 1] = p1;

    // ---- pack 21-bit order-inverted label | 11-bit index; track max & sum
    uint32_t v[8];
    float lmax = -INFINITY, lsum = 0.f;
#pragma unroll
    for (int s = 0; s < 8; ++s) {
        uint32_t u    = __float_as_uint(lv[s]);
        uint32_t mask = (u & 0x80000000u) ? 0xFFFFFFFFu : 0x80000000u;
        uint32_t inv  = ~(u ^ mask);          // ascending u32 == descending label
        v[s] = (inv & 0xFFFFF800u) | (uint32_t)(base + s);
        lmax = fmaxf(lmax, pv[s]);
        lsum += pv[s];
    }

    // ---- block reduce max & sum
#pragma unroll
    for (int o = 32; o > 0; o >>= 1) {
        lmax = fmaxf(lmax, __shfl_down(lmax, o, 64));
        lsum += __shfl_down(lsum, o, 64);
    }
    if (lane == 0) { wmax[wave] = lmax; wsum[wave] = lsum; }
    __syncthreads();
    const float m      = fmaxf(fmaxf(wmax[0], wmax[1]), fmaxf(wmax[2], wmax[3]));
    const float rowsum = wsum[0] + wsum[1] + wsum[2] + wsum[3];

    // ================= bitonic sort (ascending u32) =================
    // Phase 1: k=2,4 compile-time directions; k=8 thread-uniform
    ce(v[0], v[1], true);  ce(v[2], v[3], false);
    ce(v[4], v[5], true);  ce(v[6], v[7], false);

    ce(v[0], v[2], true);  ce(v[1], v[3], true);
    ce(v[4], v[6], false); ce(v[5], v[7], false);
    ce(v[0], v[1], true);  ce(v[2], v[3], true);
    ce(v[4], v[5], false); ce(v[6], v[7], false);

    {
        const bool up8 = ((t & 1) == 0);
        ce(v[0], v[4], up8); ce(v[1], v[5], up8);
        ce(v[2], v[6], up8); ce(v[3], v[7], up8);
        ce(v[0], v[2], up8); ce(v[1], v[3], up8);
        ce(v[4], v[6], up8); ce(v[5], v[7], up8);
        ce(v[0], v[1], up8); ce(v[2], v[3], up8);
        ce(v[4], v[5], up8); ce(v[6], v[7], up8);
    }

    // Phase 2
    { const bool up = ((base & 16)  == 0); shuffle_stages<1>(v, t, up);  tail(v, up); }
    { const bool up = ((base & 32)  == 0); shuffle_stages<2>(v, t, up);  tail(v, up); }
    { const bool up = ((base & 64)  == 0); shuffle_stages<4>(v, t, up);  tail(v, up); }
    { const bool up = ((base & 128) == 0); shuffle_stages<8>(v, t, up);  tail(v, up); }
    { const bool up = ((base & 256) == 0); shuffle_stages<16>(v, t, up); tail(v, up); }
    { const bool up = ((base & 512) == 0); shuffle_stages<32>(v, t, up); tail(v, up); }
    { const bool up = ((base & 1024) == 0);
      lds_stage(v, up, t, 64, xbuf);
      shuffle_stages<32>(v, t, up); tail(v, up); }
    { const bool up = ((base & 2048) == 0);
      lds_stage(v, up, t, 128, xbuf);
      lds_stage(v, up, t, 64,  xbuf);
      shuffle_stages<32>(v, t, up); tail(v, up); }

    // ================= epilogue =================
    // gather preds by sorted index, e_s = exp(pred_sorted - m)
    float e[8];
    float csum = 0.f;
#pragma unroll
    for (int s = 0; s < 8; ++s) {
        float ps = predb[v[s] & 0x7FFu];
        e[s] = __expf(ps - m);
        csum += e[s];
    }

    // inclusive suffix scan of chunk sums within wave
    float x = csum;
#pragma unroll
    for (int o = 1; o < 64; o <<= 1) {
        float y = __shfl_down(x, o, 64);
        if (lane + o < 64) x += y;
    }
    if (lane == 0) wtt[wave] = x;
    __syncthreads();
    float after = 0.f;
#pragma unroll
    for (int w = 0; w < NWAVES; ++w)
        if (w > wave) after += wtt[w];

    // exclusive suffix for this chunk, serial log-accumulate
    float run = (x - csum) + after;
    float acc = 0.f;
#pragma unroll
    for (int s = 7; s >= 0; --s) {
        run += e[s];
        acc += __logf(run);
    }

    // ---- block reduce, one atomic per row
#pragma unroll
    for (int o = 32; o > 0; o >>= 1) acc += __shfl_down(acc, o, 64);
    if (lane == 0) wred[wave] = acc;
    __syncthreads();
    if (t == 0) {
        float total = wred[0] + wred[1] + wred[2] + wred[3]
                      + (float)ROW_LEN * m - rowsum;
        atomicAdd(out, total);
    }
}

extern "C" void kernel_launch(void* const* d_in, const int* in_sizes, int n_in,
                              void* d_out, int out_size, void* d_ws, size_t ws_size,
                              hipStream_t stream) {
    const float* preds  = (const float*)d_in[0];
    const float* labels = (const float*)d_in[1];
    float* out = (float*)d_out;
    const int total = in_sizes[0];
    const int nrows = total / ROW_LEN;

    hipMemsetAsync(d_out, 0, (size_t)out_size * sizeof(float), stream);
    listmle_kernel<<<nrows, THREADS, 0, stream>>>(preds, labels, out, nrows);
}